// Round 4
// baseline (85.885 us; speedup 1.0000x reference)
//
#include <hip/hip_runtime.h>

typedef float f32x4 __attribute__((ext_vector_type(4)));
typedef _Float16 f16x8 __attribute__((ext_vector_type(8)));
typedef _Float16 f16x4 __attribute__((ext_vector_type(4)));
typedef int i32x4 __attribute__((ext_vector_type(4)));
typedef int i32x2 __attribute__((ext_vector_type(2)));

#define WAVES 4

__device__ __forceinline__ f32x4 mfma16(f16x8 a, f16x8 b, f32x4 c) {
    return __builtin_amdgcn_mfma_f32_16x16x32_f16(a, b, c, 0, 0, 0);
}

// 8 consecutive k-elements (fp32) -> fp16 fragment, RNE
__device__ __forceinline__ f16x8 cvt8(f32x4 a, f32x4 b) {
    f16x8 h;
#pragma unroll
    for (int j = 0; j < 4; ++j) { h[j] = (_Float16)a[j]; h[j + 4] = (_Float16)b[j]; }
    return h;
}

// relu + pack one accumulator quad (4 f32, regs r=0..3) -> 2 dwords of fp16 pairs
__device__ __forceinline__ i32x2 relu_pk2(f32x4 a) {
    f16x4 v;
#pragma unroll
    for (int j = 0; j < 4; ++j) v[j] = (_Float16)fmaxf(a[j], 0.0f);
    return __builtin_bit_cast(i32x2, v);
}

// B-fragment for step s = concat of two packed quads -- pure register move.
__device__ __forceinline__ f16x8 cat(i32x2 a, i32x2 b) {
    i32x4 v; v[0] = a[0]; v[1] = a[1]; v[2] = b[0]; v[3] = b[1];
    return __builtin_bit_cast(f16x8, v);
}

// One wave processes TWO 16-row batch tiles per iteration.
// Orientation: D[m=neuron][n=batch]. mfma_f32_16x16x32_f16 layouts (HW-verified R1/R2):
//   A: lane l supplies A[l&15][8*(l>>4)+j]
//   B: lane l supplies B[8*(l>>4)+j][l&15]
//   D: lane l holds   D[4*(l>>4)+r][l&15]
// Hidden-layer transition uses the neuron permutation
//   phi(32s+8g+j) = 16*(2s+(j>>2)) + 4g + (j&3)
// so each lane's B-fragment for step s is exactly its own packed accumulators
// concat(pk[2s], pk[2s+1]) -- zero cross-lane traffic. W1/W2 COLUMNS are loaded
// phi-gathered (still two contiguous f32x4 loads per fragment: +32s+4g and +16).
__global__ __launch_bounds__(256, 4) void mlp_kernel(
    const float* __restrict__ X, const float* __restrict__ W0,
    const float* __restrict__ W1, const float* __restrict__ W2,
    float* __restrict__ Y, int ntiles)
{
    const int tid  = threadIdx.x;
    const int wid  = tid >> 6;
    const int lane = tid & 63;
    const int b16  = lane & 15;
    const int g    = lane >> 4;

    // ---- fp16 weight fragments (RNE), loaded once per wave ----
    f16x8 w0[4], w1[4][2], w2[2];
#pragma unroll
    for (int t = 0; t < 4; ++t) {
        const float* p = W0 + (16 * t + b16) * 32 + 8 * g;   // cols unpermuted (input dim)
        w0[t] = cvt8(*(const f32x4*)p, *(const f32x4*)(p + 4));
    }
#pragma unroll
    for (int t = 0; t < 4; ++t) {
#pragma unroll
        for (int s = 0; s < 2; ++s) {
            const float* p = W1 + (16 * t + b16) * 64 + 32 * s + 4 * g;  // phi-gathered cols
            w1[t][s] = cvt8(*(const f32x4*)p, *(const f32x4*)(p + 16));
        }
    }
#pragma unroll
    for (int s = 0; s < 2; ++s) {
        const float* p = W2 + b16 * 64 + 32 * s + 4 * g;                 // phi-gathered cols
        w2[s] = cvt8(*(const f32x4*)p, *(const f32x4*)(p + 16));
    }

    const int xoff = b16 * 32 + 8 * g;    // float offset within a 16x32 input tile
    const int yoff = b16 * 16 + 4 * g;    // float offset within a 16x16 output tile

    const int npairs = (ntiles + 1) >> 1;
    const int gwid = blockIdx.x * WAVES + wid;
    const int gstr = gridDim.x * WAVES;
    if (gwid >= npairs) return;

    int pair = gwid;
    const float* xp = X + (size_t)(2 * pair) * 512 + xoff;
    size_t off1 = (2 * pair + 1 < ntiles) ? 512 : 0;     // duplicate-safe odd tail
    f32x4 x00 = *(const f32x4*)xp;          f32x4 x01 = *(const f32x4*)(xp + 4);
    f32x4 x10 = *(const f32x4*)(xp + off1); f32x4 x11 = *(const f32x4*)(xp + off1 + 4);

    while (true) {
        const int next = pair + gstr;
        const bool have_next = next < npairs;
        const int pf = have_next ? next : pair;
        const float* np = X + (size_t)(2 * pf) * 512 + xoff;
        const size_t noff1 = (2 * pf + 1 < ntiles) ? 512 : 0;
        f32x4 n00 = *(const f32x4*)np;           f32x4 n01 = *(const f32x4*)(np + 4);
        f32x4 n10 = *(const f32x4*)(np + noff1); f32x4 n11 = *(const f32x4*)(np + noff1 + 4);

        // ---- layer 1: K=32, 4 m-quads, both tiles ----
        i32x2 pk[2][4];
#pragma unroll
        for (int u = 0; u < 2; ++u) {
            f16x8 xa = cvt8(u ? x10 : x00, u ? x11 : x01);
#pragma unroll
            for (int t = 0; t < 4; ++t) {
                f32x4 z = {0.f, 0.f, 0.f, 0.f};
                z = mfma16(w0[t], xa, z);
                pk[u][t] = relu_pk2(z);
            }
        }

        // ---- layers 2+3 per tile (keeps peak VGPR low) ----
#pragma unroll
        for (int u = 0; u < 2; ++u) {
            f32x4 c[4];
#pragma unroll
            for (int t = 0; t < 4; ++t) c[t] = (f32x4){0.f, 0.f, 0.f, 0.f};
            const f16x8 f0 = cat(pk[u][0], pk[u][1]);   // step s=0, lane-local
#pragma unroll
            for (int t = 0; t < 4; ++t) c[t] = mfma16(w1[t][0], f0, c[t]);
            const f16x8 f1 = cat(pk[u][2], pk[u][3]);   // step s=1
#pragma unroll
            for (int t = 0; t < 4; ++t) c[t] = mfma16(w1[t][1], f1, c[t]);

            i32x2 q[4];
#pragma unroll
            for (int t = 0; t < 4; ++t) q[t] = relu_pk2(c[t]);

            f32x4 o = {0.f, 0.f, 0.f, 0.f};
            o = mfma16(w2[0], cat(q[0], q[1]), o);
            o = mfma16(w2[1], cat(q[2], q[3]), o);

            float* yp = Y + (size_t)(2 * pair) * 256 + yoff;
            *(f32x4*)(yp + (u ? (off1 ? 256 : 0) : 0)) = o;
        }

        if (!have_next) break;
        pair = next;
        off1 = noff1;
        x00 = n00; x01 = n01; x10 = n10; x11 = n11;
    }
}

extern "C" void kernel_launch(void* const* d_in, const int* in_sizes, int n_in,
                              void* d_out, int out_size, void* d_ws, size_t ws_size,
                              hipStream_t stream) {
    const float* X  = (const float*)d_in[0];
    const float* W0 = (const float*)d_in[1];
    const float* W1 = (const float*)d_in[2];
    const float* W2 = (const float*)d_in[3];
    float* Y = (float*)d_out;

    const int batch  = in_sizes[0] / 32;
    const int ntiles = batch / 16;               // 125,000
    const int npairs = (ntiles + 1) >> 1;        // 62,500

    int blocks = 1024;                           // 4 blocks/CU resident (no LDS, VGPR<=128)
    if (blocks * WAVES > npairs) blocks = (npairs + WAVES - 1) / WAVES;

    hipLaunchKernelGGL(mlp_kernel, dim3(blocks), dim3(256), 0, stream,
                       X, W0, W1, W2, Y, ntiles);
}

// Round 5
// 72.649 us; speedup vs baseline: 1.1822x; 1.1822x over previous
//
#include <hip/hip_runtime.h>

typedef float f32x4 __attribute__((ext_vector_type(4)));
typedef _Float16 f16x8 __attribute__((ext_vector_type(8)));
typedef _Float16 f16x4 __attribute__((ext_vector_type(4)));
typedef int i32x4 __attribute__((ext_vector_type(4)));
typedef int i32x2 __attribute__((ext_vector_type(2)));

#define WAVES 4

__device__ __forceinline__ f32x4 mfma16(f16x8 a, f16x8 b, f32x4 c) {
    return __builtin_amdgcn_mfma_f32_16x16x32_f16(a, b, c, 0, 0, 0);
}

// 8 consecutive k-elements (fp32) -> fp16 fragment, RNE
__device__ __forceinline__ f16x8 cvt8(f32x4 a, f32x4 b) {
    f16x8 h;
#pragma unroll
    for (int j = 0; j < 4; ++j) { h[j] = (_Float16)a[j]; h[j + 4] = (_Float16)b[j]; }
    return h;
}

// relu + pack one accumulator quad (4 f32) -> 2 dwords of fp16 pairs
__device__ __forceinline__ i32x2 relu_pk2(f32x4 a) {
    f16x4 v;
#pragma unroll
    for (int j = 0; j < 4; ++j) v[j] = (_Float16)fmaxf(a[j], 0.0f);
    return __builtin_bit_cast(i32x2, v);
}

// B-fragment = concat of two packed quads -- pure register move.
__device__ __forceinline__ f16x8 cat(i32x2 a, i32x2 b) {
    i32x4 v; v[0] = a[0]; v[1] = a[1]; v[2] = b[0]; v[3] = b[1];
    return __builtin_bit_cast(f16x8, v);
}

// Orientation: D[m=neuron][n=batch]. mfma_f32_16x16x32_f16 layouts (HW-verified R1-R4):
//   A: lane l supplies A[l&15][8*(l>>4)+j]
//   B: lane l supplies B[8*(l>>4)+j][l&15]
//   D: lane l holds   D[4*(l>>4)+r][l&15]
// Hidden-neuron permutation phi(32s+8g+j) = 16*(2s+(j>>2)) + 4g + (j&3) makes each
// lane's next-layer B-fragment its own packed accumulators (zero cross-lane traffic);
// W1/W2 columns are loaded phi-gathered (two contiguous f32x4 loads per fragment).
//
// Memory structure: 2-deep prefetch ping-pong (pendA/pendB, 8KB in flight per wave),
// per-tile compute to bound transient VGPR, nontemporal Y stores.
__global__ __launch_bounds__(256, 4) void mlp_kernel(
    const float* __restrict__ X, const float* __restrict__ W0,
    const float* __restrict__ W1, const float* __restrict__ W2,
    float* __restrict__ Y, int ntiles)
{
    const int tid  = threadIdx.x;
    const int wid  = tid >> 6;
    const int lane = tid & 63;
    const int b16  = lane & 15;
    const int g    = lane >> 4;

    // ---- fp16 weight fragments (RNE), loaded once per wave ----
    f16x8 w0[4], w1[4][2], w2[2];
#pragma unroll
    for (int t = 0; t < 4; ++t) {
        const float* p = W0 + (16 * t + b16) * 32 + 8 * g;   // cols unpermuted (input dim)
        w0[t] = cvt8(*(const f32x4*)p, *(const f32x4*)(p + 4));
    }
#pragma unroll
    for (int t = 0; t < 4; ++t) {
#pragma unroll
        for (int s = 0; s < 2; ++s) {
            const float* p = W1 + (16 * t + b16) * 64 + 32 * s + 4 * g;  // phi-gathered
            w1[t][s] = cvt8(*(const f32x4*)p, *(const f32x4*)(p + 16));
        }
    }
#pragma unroll
    for (int s = 0; s < 2; ++s) {
        const float* p = W2 + b16 * 64 + 32 * s + 4 * g;                 // phi-gathered
        w2[s] = cvt8(*(const f32x4*)p, *(const f32x4*)(p + 16));
    }

    const int xoff = b16 * 32 + 8 * g;    // float offset within a 16x32 input tile
    const int yoff = b16 * 16 + 4 * g;    // float offset within a 16x16 output tile

    const int npairs = (ntiles + 1) >> 1;
    const int gwid = blockIdx.x * WAVES + wid;
    const int G    = gridDim.x * WAVES;
    if (gwid >= npairs) return;

#define LOADP(dst0, dst1, dst2, dst3, p)                                        \
    {                                                                           \
        const int pc = ((p) < npairs) ? (p) : gwid;  /* clamped, always valid */\
        const float* xp_ = X + (size_t)(2 * pc) * 512 + xoff;                   \
        const size_t o1_ = (2 * pc + 1 < ntiles) ? 512 : 0;                     \
        dst0 = *(const f32x4*)xp_;        dst1 = *(const f32x4*)(xp_ + 4);      \
        dst2 = *(const f32x4*)(xp_ + o1_); dst3 = *(const f32x4*)(xp_ + o1_ + 4); \
    }

    // per-tile compute: fp16 input fragment -> 16 outputs, nontemporal store
#define COMPUTE_STORE(xa, p, u)                                                 \
    {                                                                           \
        i32x2 pk[4];                                                            \
        _Pragma("unroll")                                                       \
        for (int t = 0; t < 4; ++t) {                                           \
            f32x4 z = {0.f, 0.f, 0.f, 0.f};                                     \
            z = mfma16(w0[t], xa, z);                                           \
            pk[t] = relu_pk2(z);                                                \
        }                                                                       \
        f32x4 c[4];                                                             \
        _Pragma("unroll")                                                       \
        for (int t = 0; t < 4; ++t) c[t] = (f32x4){0.f, 0.f, 0.f, 0.f};         \
        const f16x8 f0 = cat(pk[0], pk[1]);                                     \
        _Pragma("unroll")                                                       \
        for (int t = 0; t < 4; ++t) c[t] = mfma16(w1[t][0], f0, c[t]);          \
        const f16x8 f1 = cat(pk[2], pk[3]);                                     \
        _Pragma("unroll")                                                       \
        for (int t = 0; t < 4; ++t) c[t] = mfma16(w1[t][1], f1, c[t]);          \
        i32x2 q[4];                                                             \
        _Pragma("unroll")                                                       \
        for (int t = 0; t < 4; ++t) q[t] = relu_pk2(c[t]);                      \
        f32x4 o = {0.f, 0.f, 0.f, 0.f};                                         \
        o = mfma16(w2[0], cat(q[0], q[1]), o);                                  \
        o = mfma16(w2[1], cat(q[2], q[3]), o);                                  \
        float* yp_ = Y + ((size_t)(2 * (p)) + (u)) * 256 + yoff;                \
        __builtin_nontemporal_store(o, (f32x4*)yp_);                            \
    }

    int p0 = gwid;          // processed from pendA; always valid at loop top
    int p1 = p0 + G;        // processed from pendB; may be invalid (checked)

    f32x4 a0, a1, a2, a3;   // pendA
    f32x4 b0, b1, b2, b3;   // pendB
    LOADP(a0, a1, a2, a3, p0)
    LOADP(b0, b1, b2, b3, p1)

    while (true) {
        // ---- half A: consume pendA (pair p0), refill for p0+2G ----
        {
            const f16x8 xa = cvt8(a0, a1);
            const f16x8 xb = cvt8(a2, a3);
            const int p2 = p0 + 2 * G;
            LOADP(a0, a1, a2, a3, p2)
            COMPUTE_STORE(xa, p0, 0)
            COMPUTE_STORE(xb, p0, 1)
            p0 = p2;
        }
        if (p1 >= npairs) break;

        // ---- half B: consume pendB (pair p1), refill for p1+2G ----
        {
            const f16x8 xa = cvt8(b0, b1);
            const f16x8 xb = cvt8(b2, b3);
            const int p3 = p1 + 2 * G;
            LOADP(b0, b1, b2, b3, p3)
            COMPUTE_STORE(xa, p1, 0)
            COMPUTE_STORE(xb, p1, 1)
            p1 = p3;
        }
        if (p0 >= npairs) break;
    }
#undef LOADP
#undef COMPUTE_STORE
}

extern "C" void kernel_launch(void* const* d_in, const int* in_sizes, int n_in,
                              void* d_out, int out_size, void* d_ws, size_t ws_size,
                              hipStream_t stream) {
    const float* X  = (const float*)d_in[0];
    const float* W0 = (const float*)d_in[1];
    const float* W1 = (const float*)d_in[2];
    const float* W2 = (const float*)d_in[3];
    float* Y = (float*)d_out;

    const int batch  = in_sizes[0] / 32;
    const int ntiles = batch / 16;               // 125,000
    const int npairs = (ntiles + 1) >> 1;        // 62,500

    int blocks = 1024;                           // 4 blocks/CU resident (no LDS, VGPR<=128)
    if (blocks * WAVES > npairs) blocks = (npairs + WAVES - 1) / WAVES;

    hipLaunchKernelGGL(mlp_kernel, dim3(blocks), dim3(256), 0, stream,
                       X, W0, W1, W2, Y, ntiles);
}